// Round 10
// baseline (90.241 us; speedup 1.0000x reference)
//
#include <hip/hip_runtime.h>

// Problem constants
#define NIMG 4
#define CCH  3
#define KCH  21
#define HIN  128
#define WIN  128
#define OH   64
#define OW   64
#define PPX  (OH*OW)          // 4096 pixels after 0.5x downsample
#define NPIX (NIMG*PPX)       // 16384 = 2^14

// feature prescale: sqrt(2)*sqrt(0.5*log2(e)) so that
//   exp(-0.5*d2) == exp2( v_i . v_j - h_i - h_j ),  h = 0.5*|v|^2
#define PRE2 1.20112241f

#define RECW  32              // halfs per record (64B): seg 21+11z / feat 5+27z

#define BLOCK  256
#define JCHUNK 256            // j-pixels per block
#define IBLK   64             // i-pixels per block (16 per wave)

#define NSLOT  64             // partial-sum cachelines (atomic spreading)

typedef _Float16 half_t;
typedef half_t half8  __attribute__((ext_vector_type(8)));
typedef float  f32x4v __attribute__((ext_vector_type(4)));

// ws layout (bytes): segH(1MB) | featH(1MB) | sqF(64KB) | slots
#define FEATH_OFF ((size_t)NPIX*RECW*2)
#define SQF_OFF   (FEATH_OFF + (size_t)NPIX*RECW*2)
#define SLOT_OFF  (SQF_OFF + (size_t)NPIX*4)

// ---------------------------------------------------------------------------
// Prep: pixel-fast indexing (g = q*NPIX + pl), q in [0,36).
// q<32  -> segH[pl*32+q] = pooled seg * ROI (q<21) else 0   [zeros in memory
//          let MFMA quads read their k-slice with no masking]
// q==32 -> 5 prescaled features as half8 {f,0,0,0} + fp32 h = 0.5|v|^2 from
//          the f16-ROUNDED v so E_ii == 0 exactly
// q==33/34/35 -> zero half8 at featH[pl*32 + 8/16/24]; q==35 also zeros slots
// ---------------------------------------------------------------------------
__global__ __launch_bounds__(BLOCK) void crf_prep(const float* __restrict__ img,
                                                  const float* __restrict__ seg,
                                                  const float* __restrict__ roi,
                                                  half_t* __restrict__ segH,
                                                  half_t* __restrict__ featH,
                                                  float* __restrict__ sqF,
                                                  float* __restrict__ slots) {
    int g  = blockIdx.x * BLOCK + threadIdx.x;    // [0, 36*NPIX)
    int q  = g >> 14;                             // slow: record element
    int pl = g & (NPIX - 1);                      // fast: linear pixel
    int n  = pl >> 12;
    int p  = pl & (PPX - 1);
    int y = p >> 6, x = p & 63;
    int y2 = 2 * y, x2 = 2 * x;

    if (q < RECW) {
        float v = 0.0f;
        if (q < KCH) {
            const float* s0 = seg + (((size_t)n * KCH + q) * HIN + y2) * WIN + x2;
            float r = roi[((size_t)n * HIN + y2) * WIN + x2];
            v = 0.25f * (s0[0] + s0[1] + s0[WIN] + s0[WIN + 1]) * r;
        }
        segH[(size_t)pl * RECW + q] = (half_t)v;
    } else if (q == 32) {
        float fx = (float)x * (PRE2 / 50.0f);
        float fy = (float)y * (PRE2 / 50.0f);
        const size_t ib = (((size_t)n * CCH) * HIN + y2) * WIN + x2;
        float fr = img[ib]                         * (PRE2 / 0.15f);
        float fg = img[ib + (size_t)HIN * WIN]     * (PRE2 / 0.15f);
        float fb = img[ib + 2 * (size_t)HIN * WIN] * (PRE2 / 0.15f);
        half_t h0 = (half_t)fx, h1 = (half_t)fy, h2 = (half_t)fr,
               h3 = (half_t)fg, h4 = (half_t)fb;
        half8 fh = {h0, h1, h2, h3, h4, (half_t)0, (half_t)0, (half_t)0};
        *(half8*)(featH + (size_t)pl * RECW) = fh;
        float a0 = (float)h0, a1 = (float)h1, a2 = (float)h2,
              a3 = (float)h3, a4 = (float)h4;
        sqF[pl] = 0.5f * (a0 * a0 + a1 * a1 + a2 * a2 + a3 * a3 + a4 * a4);
    } else {
        half8 z = {};
        *(half8*)(featH + (size_t)pl * RECW + (q - 32) * 8) = z;
        if (q == 35 && pl < NSLOT) slots[pl * 16] = 0.0f;
    }
}

// ---------------------------------------------------------------------------
// Main: BARRIER-FREE streaming (R7 showed the old version 80% idle behind
// staging+syncthreads in tiny blocks).  B-fragments load DIRECTLY from
// global: per jt a wave reads 64 lanes x 16B = 1KB contiguous (perfectly
// coalesced), L1-shared across the block's 4 waves, L2-shared across the 17
// blocks per J-chunk.  Zero k-slices come from memory padding -- no masking,
// no LDS tile, no __syncthreads in the hot loop.
//   E  = mfma(afeat, bfeat, c4)   with c4[r] = -h_i(row r) - h_j(col)
//   Gs = mfma(aseg,  bseg,  0);   term = exp2(E) * Gs
// Triangular launch (544 blocks/img): strictly-upper blocks weight 2.
// ---------------------------------------------------------------------------
__global__ __launch_bounds__(BLOCK, 4) void crf_main(const half_t* __restrict__ segH,
                                                     const half_t* __restrict__ featH,
                                                     const float* __restrict__ sqF,
                                                     float* __restrict__ slots) {
    const int bx = blockIdx.x;   // [0, 544)
    const int n  = blockIdx.y;

    // triangular decode: g = I>>2 group; 4 I's per group, 16-g J's each
    int g = 0;
#pragma unroll
    for (int t = 1; t < 16; ++t) {
        int off = 64 * t - 2 * t * (t - 1);
        if (bx >= off) g = t;
    }
    int rem = bx - (64 * g - 2 * g * (g - 1));
    int c   = 16 - g;
    int iq  = (rem >= c) + (rem >= 2 * c) + (rem >= 3 * c);
    int I   = 4 * g + iq;
    int J   = g + (rem - iq * c);
    const bool diag = (J == (I >> 2));

    const half_t* segN  = segH  + (size_t)n * PPX * RECW;
    const half_t* featN = featH + (size_t)n * PPX * RECW;
    const float*  sqN   = sqF   + (size_t)n * PPX;

    __shared__ float wsum[BLOCK / 64];

    const int tid  = threadIdx.x;
    const int lane = tid & 63, wv = tid >> 6;
    const int m = lane & 15, quad = lane >> 4;
    const int i0 = I * IBLK + wv * 16;
    const int j0 = J * JCHUNK;

    // A-frags from global (zero k-slices are real zeros in memory)
    half8 aseg  = *(const half8*)(segN  + (size_t)(i0 + m) * RECW + quad * 8);
    half8 afeat = *(const half8*)(featN + (size_t)(i0 + m) * RECW + quad * 8);
    f32x4v hi   = *(const f32x4v*)(sqN + i0 + quad * 4);  // rows quad*4..+3
    f32x4v nh = -hi;

    // per-lane B pointers, stride 16 records per j-tile
    const half_t* bsp = segN  + (size_t)(j0 + m) * RECW + quad * 8;
    const half_t* bfp = featN + (size_t)(j0 + m) * RECW + quad * 8;
    const float*  hp  = sqN + j0 + m;

    float acc0 = 0.0f, acc1 = 0.0f, acc2 = 0.0f, acc3 = 0.0f;
    const f32x4v zero4 = {0.0f, 0.0f, 0.0f, 0.0f};

#pragma unroll 4
    for (int jt = 0; jt < JCHUNK / 16; ++jt) {
        half8 bseg = *(const half8*)(bsp + (size_t)jt * 16 * RECW);
        half8 bft  = *(const half8*)(bfp + (size_t)jt * 16 * RECW);
        float hc   = hp[jt * 16];

        f32x4v c4 = {nh[0] - hc, nh[1] - hc, nh[2] - hc, nh[3] - hc};
        f32x4v E  = __builtin_amdgcn_mfma_f32_16x16x32_f16(afeat, bft, c4, 0, 0, 0);
        f32x4v Gs = __builtin_amdgcn_mfma_f32_16x16x32_f16(aseg, bseg, zero4, 0, 0, 0);

        if (!diag) {
            acc0 = fmaf(__builtin_amdgcn_exp2f(E[0]), Gs[0], acc0);
            acc1 = fmaf(__builtin_amdgcn_exp2f(E[1]), Gs[1], acc1);
            acc2 = fmaf(__builtin_amdgcn_exp2f(E[2]), Gs[2], acc2);
            acc3 = fmaf(__builtin_amdgcn_exp2f(E[3]), Gs[3], acc3);
        } else {
            const int jg = j0 + jt * 16 + m;
            const int ia = i0 + quad * 4;
            float s0 = (jg > ia)     ? 1.0f : ((jg == ia)     ? 0.0f : -100000.0f);
            float s1 = (jg > ia + 1) ? 1.0f : ((jg == ia + 1) ? 0.0f : -100000.0f);
            float s2 = (jg > ia + 2) ? 1.0f : ((jg == ia + 2) ? 0.0f : -100000.0f);
            float s3 = (jg > ia + 3) ? 1.0f : ((jg == ia + 3) ? 0.0f : -100000.0f);
            acc0 = fmaf(__builtin_amdgcn_exp2f(E[0] + s0), Gs[0], acc0);
            acc1 = fmaf(__builtin_amdgcn_exp2f(E[1] + s1), Gs[1], acc1);
            acc2 = fmaf(__builtin_amdgcn_exp2f(E[2] + s2), Gs[2], acc2);
            acc3 = fmaf(__builtin_amdgcn_exp2f(E[3] + s3), Gs[3], acc3);
        }
    }

    // reduce: thread -> wave -> block -> spread atomic slot
    float racc = (acc0 + acc1) + (acc2 + acc3);
#pragma unroll
    for (int off = 32; off > 0; off >>= 1) racc += __shfl_down(racc, off);
    if (lane == 0) wsum[wv] = racc;
    __syncthreads();
    if (tid == 0) {
        float s = wsum[0] + wsum[1] + wsum[2] + wsum[3];
        if (!diag) s *= 2.0f;              // strictly-upper counts (i,j)+(j,i)
        int slot = (bx + 544 * n) & (NSLOT - 1);
        atomicAdd(&slots[slot * 16], s);
    }
}

// ---------------------------------------------------------------------------
// Final: one wave sums the 64 slots and writes the scalar output.
// ---------------------------------------------------------------------------
__global__ __launch_bounds__(64) void crf_final(const float* __restrict__ slots,
                                                float* __restrict__ out) {
    int lane = threadIdx.x;
    float v = slots[lane * 16];
#pragma unroll
    for (int off = 32; off > 0; off >>= 1) v += __shfl_down(v, off);
    if (lane == 0) out[0] = v * (-5.0e-10f);   // WEIGHT * (-sum/NIMG)
}

extern "C" void kernel_launch(void* const* d_in, const int* in_sizes, int n_in,
                              void* d_out, int out_size, void* d_ws, size_t ws_size,
                              hipStream_t stream) {
    const float* img = (const float*)d_in[0];
    const float* seg = (const float*)d_in[1];
    const float* roi = (const float*)d_in[2];
    float* out = (float*)d_out;

    char* wsb = (char*)d_ws;                    // ~2.07 MB of ws used
    half_t* segH  = (half_t*)(wsb);
    half_t* featH = (half_t*)(wsb + FEATH_OFF);
    float*  sqF   = (float*)(wsb + SQF_OFF);
    float*  slots = (float*)(wsb + SLOT_OFF);

    crf_prep<<<(NPIX * 36) / BLOCK, BLOCK, 0, stream>>>(img, seg, roi,
                                                        segH, featH, sqF, slots);

    dim3 grid(544, NIMG);                       // sum_g 4*(16-g) = 544 per image
    crf_main<<<grid, BLOCK, 0, stream>>>(segH, featH, sqF, slots);

    crf_final<<<1, 64, 0, stream>>>(slots, out);
}

// Round 11
// 79.846 us; speedup vs baseline: 1.1302x; 1.1302x over previous
//
#include <hip/hip_runtime.h>

// Problem constants
#define NIMG 4
#define CCH  3
#define KCH  21
#define HIN  128
#define WIN  128
#define OH   64
#define OW   64
#define PPX  (OH*OW)          // 4096 pixels after 0.5x downsample
#define NPIX (NIMG*PPX)       // 16384 = 2^14

// feature prescale: sqrt(2)*sqrt(0.5*log2(e)) so that
//   exp(-0.5*d2) == exp2( v_i . v_j - h_i - h_j ),  h = 0.5*|v|^2
#define PRE2 1.20112241f

#define SEGW  24              // halfs per pixel: 21 seg + 3 zero (48B)
#define FEATW 8               // halfs per pixel: 5 feat + 3 zero (16B)

#define BLOCK  1024           // 16 waves -- fat blocks amortize staging/barriers
#define JCHUNK 256            // j-pixels staged per block
#define IBLK   256            // i-pixels per block (16 per wave x 16 waves)

#define NSLOT  64             // partial-sum cachelines (atomic spreading)

typedef _Float16 half_t;
typedef half_t half8  __attribute__((ext_vector_type(8)));
typedef float  f32x4v __attribute__((ext_vector_type(4)));

// ws layout (bytes): segH | featH | sqF | slots
#define FEATH_OFF ((size_t)NPIX*SEGW*2)
#define SQF_OFF   (FEATH_OFF + (size_t)NPIX*FEATW*2)
#define SLOT_OFF  (SQF_OFF + (size_t)NPIX*4)

// ---------------------------------------------------------------------------
// Prep (R8 structure): pixel-fast indexing, coalesced reads/writes.
// q<24 -> seg channel (2x2 avg pool * nearest ROI) as f16;
// q==24 -> 5 prescaled features (padded half8) + fp32 h = 0.5|v|^2 from the
// f16-ROUNDED v so E_ii == 0 exactly;  q==25, pl<64 -> zero slots.
// ---------------------------------------------------------------------------
__global__ __launch_bounds__(256) void crf_prep(const float* __restrict__ img,
                                                const float* __restrict__ seg,
                                                const float* __restrict__ roi,
                                                half_t* __restrict__ segH,
                                                half_t* __restrict__ featH,
                                                float* __restrict__ sqF,
                                                float* __restrict__ slots) {
    int g  = blockIdx.x * 256 + threadIdx.x;      // [0, 32*NPIX)
    int q  = g >> 14;                             // slow: record element
    int pl = g & (NPIX - 1);                      // fast: linear pixel
    int n  = pl >> 12;
    int p  = pl & (PPX - 1);
    int y = p >> 6, x = p & 63;
    int y2 = 2 * y, x2 = 2 * x;

    if (q < SEGW) {
        float v = 0.0f;
        if (q < KCH) {
            const float* s0 = seg + (((size_t)n * KCH + q) * HIN + y2) * WIN + x2;
            float r = roi[((size_t)n * HIN + y2) * WIN + x2];
            v = 0.25f * (s0[0] + s0[1] + s0[WIN] + s0[WIN + 1]) * r;
        }
        segH[(size_t)pl * SEGW + q] = (half_t)v;
    } else if (q == 24) {
        float fx = (float)x * (PRE2 / 50.0f);
        float fy = (float)y * (PRE2 / 50.0f);
        const size_t ib = (((size_t)n * CCH) * HIN + y2) * WIN + x2;
        float fr = img[ib]                         * (PRE2 / 0.15f);
        float fg = img[ib + (size_t)HIN * WIN]     * (PRE2 / 0.15f);
        float fb = img[ib + 2 * (size_t)HIN * WIN] * (PRE2 / 0.15f);
        half_t h0 = (half_t)fx, h1 = (half_t)fy, h2 = (half_t)fr,
               h3 = (half_t)fg, h4 = (half_t)fb;
        half8 fh = {h0, h1, h2, h3, h4, (half_t)0, (half_t)0, (half_t)0};
        *(half8*)(featH + (size_t)pl * FEATW) = fh;
        float a0 = (float)h0, a1 = (float)h1, a2 = (float)h2,
              a3 = (float)h3, a4 = (float)h4;
        sqF[pl] = 0.5f * (a0 * a0 + a1 * a1 + a2 * a2 + a3 * a3 + a4 * a4);
    } else if (q == 25) {
        if (pl < NSLOT) slots[pl * 16] = 0.0f;    // one slot per cacheline
    }
}

// ---------------------------------------------------------------------------
// Main: 1024-thread blocks (16 waves), 256-i block x 256-j chunk.
// One LDS staging + ONE barrier serves 16 waves (4x fewer blocks than the
// 256-thread version at the same full occupancy: 2 blocks/CU = 32 waves/CU).
// Per 16x16 tile: E = mfma(afeat,bfeat,c4) (c4 = -h_i - h_j), Gs =
// mfma(aseg,bseg,0), term = exp2(E)*Gs; diag blocks add {+1,0,-inf} in
// log2 space.  Partials -> 64 spread cachelines; crf_final sums.
// Triangular launch: (I,J), J>=I, I,J in [0,16): 136 blocks/image.
// ---------------------------------------------------------------------------
__global__ __launch_bounds__(BLOCK, 8) void crf_main(const half_t* __restrict__ segH,
                                                     const half_t* __restrict__ featH,
                                                     const float* __restrict__ sqF,
                                                     float* __restrict__ slots) {
    const int bx = blockIdx.x;   // [0, 136)
    const int n  = blockIdx.y;

    // triangular decode: off(t) = 16t - t(t-1)/2; I = max t with bx >= off(t)
    int I = 0;
#pragma unroll
    for (int t = 1; t < 16; ++t) {
        int off = 16 * t - (t * (t - 1)) / 2;
        if (bx >= off) I = t;
    }
    int J = I + (bx - (16 * I - (I * (I - 1)) / 2));
    const bool diag = (J == I);

    const half_t* segN  = segH  + (size_t)n * PPX * SEGW;
    const half_t* featN = featH + (size_t)n * PPX * FEATW;
    const float*  sqN   = sqF   + (size_t)n * PPX;

    __shared__ alignas(16) half_t segJ[JCHUNK * SEGW];    // 12 KB
    __shared__ alignas(16) half_t featJ[JCHUNK * FEATW];  // 4 KB
    __shared__ alignas(16) half_t zrow[8];                // 16 B of zeros
    __shared__ float hJ[JCHUNK];                          // 1 KB
    __shared__ float wsum[BLOCK / 64];

    const int tid  = threadIdx.x;
    const int lane = tid & 63, wv = tid >> 6;             // wv in [0,16)
    const int m = lane & 15, quad = lane >> 4;
    const int i0 = I * IBLK + wv * 16;
    const int j0 = J * JCHUNK;
    const int kq = (quad < 2) ? quad : 2;   // seg k-slice (quad3 -> zero row)

    half8 hz = {};

    // A-frags from global (reused over all 16 j-tiles)
    half8 aseg  = *(const half8*)(segN  + (size_t)(i0 + m) * SEGW + kq * 8);
    half8 afeat = *(const half8*)(featN + (size_t)(i0 + m) * FEATW);
    f32x4v hi   = *(const f32x4v*)(sqN + i0 + quad * 4);  // rows quad*4..+3
    if (quad == 3) aseg  = hz;
    if (quad != 0) afeat = hz;
    f32x4v nh = -hi;

    // stage j-chunk: 768+256 vec16 + 256 floats over 1024 threads, one each
    {
        if (tid < 768)
            ((f32x4v*)segJ)[tid] = ((const f32x4v*)(segN + (size_t)j0 * SEGW))[tid];
        else if (tid < 1024 - 8) {
            int t = tid - 768;   // [0,248) covers featJ(256): overlap below
            if (t < 256)
                ((f32x4v*)featJ)[t] = ((const f32x4v*)(featN + (size_t)j0 * FEATW))[t];
        }
        // featJ tail + hJ + zrow handled by dedicated ranges:
        if (tid >= 1016) {       // last 8 threads: featJ[248..255]
            int t = tid - 1016 + 248;
            ((f32x4v*)featJ)[t] = ((const f32x4v*)(featN + (size_t)j0 * FEATW))[t];
        }
        if (tid < 256) hJ[tid] = sqN[j0 + tid];
        if (tid < 8) zrow[tid] = (half_t)0;
    }
    __syncthreads();

    // per-lane B pointers: stride over j-tiles, or pinned to the zero row
    const half_t* bsp; int bstep;
    if (quad == 3) { bsp = zrow;                       bstep = 0; }
    else           { bsp = segJ + m * SEGW + quad * 8; bstep = 16 * SEGW; }
    const half_t* bfp; int fstep;
    if (quad == 0) { bfp = featJ + m * FEATW;          fstep = 16 * FEATW; }
    else           { bfp = zrow;                       fstep = 0; }

    float acc0 = 0.0f, acc1 = 0.0f, acc2 = 0.0f, acc3 = 0.0f;
    const f32x4v zero4 = {0.0f, 0.0f, 0.0f, 0.0f};

#pragma unroll 4
    for (int jt = 0; jt < JCHUNK / 16; ++jt) {
        half8 bseg = *(const half8*)bsp;  bsp += bstep;
        half8 bft  = *(const half8*)bfp;  bfp += fstep;
        float hc = hJ[jt * 16 + m];

        f32x4v c4 = {nh[0] - hc, nh[1] - hc, nh[2] - hc, nh[3] - hc};
        f32x4v E  = __builtin_amdgcn_mfma_f32_16x16x32_f16(afeat, bft, c4, 0, 0, 0);
        f32x4v Gs = __builtin_amdgcn_mfma_f32_16x16x32_f16(aseg, bseg, zero4, 0, 0, 0);

        if (!diag) {
            acc0 = fmaf(__builtin_amdgcn_exp2f(E[0]), Gs[0], acc0);
            acc1 = fmaf(__builtin_amdgcn_exp2f(E[1]), Gs[1], acc1);
            acc2 = fmaf(__builtin_amdgcn_exp2f(E[2]), Gs[2], acc2);
            acc3 = fmaf(__builtin_amdgcn_exp2f(E[3]), Gs[3], acc3);
        } else {
            const int jg = j0 + jt * 16 + m;
            const int ia = i0 + quad * 4;
            float s0 = (jg > ia)     ? 1.0f : ((jg == ia)     ? 0.0f : -100000.0f);
            float s1 = (jg > ia + 1) ? 1.0f : ((jg == ia + 1) ? 0.0f : -100000.0f);
            float s2 = (jg > ia + 2) ? 1.0f : ((jg == ia + 2) ? 0.0f : -100000.0f);
            float s3 = (jg > ia + 3) ? 1.0f : ((jg == ia + 3) ? 0.0f : -100000.0f);
            acc0 = fmaf(__builtin_amdgcn_exp2f(E[0] + s0), Gs[0], acc0);
            acc1 = fmaf(__builtin_amdgcn_exp2f(E[1] + s1), Gs[1], acc1);
            acc2 = fmaf(__builtin_amdgcn_exp2f(E[2] + s2), Gs[2], acc2);
            acc3 = fmaf(__builtin_amdgcn_exp2f(E[3] + s3), Gs[3], acc3);
        }
    }

    // reduce: thread -> wave -> block (16 waves) -> spread atomic slot
    float racc = (acc0 + acc1) + (acc2 + acc3);
#pragma unroll
    for (int off = 32; off > 0; off >>= 1) racc += __shfl_down(racc, off);
    if (lane == 0) wsum[wv] = racc;
    __syncthreads();
    if (tid == 0) {
        float s = 0.0f;
#pragma unroll
        for (int w = 0; w < BLOCK / 64; ++w) s += wsum[w];
        if (!diag) s *= 2.0f;              // strictly-upper counts (i,j)+(j,i)
        int slot = (bx + 136 * n) & (NSLOT - 1);
        atomicAdd(&slots[slot * 16], s);
    }
}

// ---------------------------------------------------------------------------
// Final: one wave sums the 64 slots and writes the scalar output.
// ---------------------------------------------------------------------------
__global__ __launch_bounds__(64) void crf_final(const float* __restrict__ slots,
                                                float* __restrict__ out) {
    int lane = threadIdx.x;
    float v = slots[lane * 16];
#pragma unroll
    for (int off = 32; off > 0; off >>= 1) v += __shfl_down(v, off);
    if (lane == 0) out[0] = v * (-5.0e-10f);   // WEIGHT * (-sum/NIMG)
}

extern "C" void kernel_launch(void* const* d_in, const int* in_sizes, int n_in,
                              void* d_out, int out_size, void* d_ws, size_t ws_size,
                              hipStream_t stream) {
    const float* img = (const float*)d_in[0];
    const float* seg = (const float*)d_in[1];
    const float* roi = (const float*)d_in[2];
    float* out = (float*)d_out;

    char* wsb = (char*)d_ws;                    // ~1.07 MB of ws used
    half_t* segH  = (half_t*)(wsb);
    half_t* featH = (half_t*)(wsb + FEATH_OFF);
    float*  sqF   = (float*)(wsb + SQF_OFF);
    float*  slots = (float*)(wsb + SLOT_OFF);

    crf_prep<<<(NPIX * 32) / 256, 256, 0, stream>>>(img, seg, roi,
                                                    segH, featH, sqF, slots);

    dim3 grid(136, NIMG);                       // sum_t (16-t) = 136 per image
    crf_main<<<grid, BLOCK, 0, stream>>>(segH, featH, sqF, slots);

    crf_final<<<1, 64, 0, stream>>>(slots, out);
}

// Round 12
// 76.520 us; speedup vs baseline: 1.1793x; 1.0435x over previous
//
#include <hip/hip_runtime.h>

// Problem constants
#define NIMG 4
#define CCH  3
#define KCH  21
#define HIN  128
#define WIN  128
#define OH   64
#define OW   64
#define PPX  (OH*OW)          // 4096 pixels after 0.5x downsample
#define NPIX (NIMG*PPX)       // 16384 = 2^14

// feature prescale: sqrt(2)*sqrt(0.5*log2(e)) so that
//   exp(-0.5*d2) == exp2( v_i . v_j - h_i - h_j ),  h = 0.5*|v|^2
#define PRE2 1.20112241f

#define SEGW  24              // halfs per pixel: 21 seg + 3 zero (48B)
#define FEATW 8               // halfs per pixel: 5 feat + 3 zero (16B)

#define BLOCK  256
#define JCHUNK 128            // j-pixels staged per block (fine blocks: small T_b)
#define IBLK   64             // i-pixels per block (16 per wave)

#define NSLOT  64             // partial-sum cachelines (atomic spreading)
#define BPI    1056           // triangular blocks per image (see decode)

typedef _Float16 half_t;
typedef half_t half8  __attribute__((ext_vector_type(8)));
typedef float  f32x4v __attribute__((ext_vector_type(4)));

// ws layout (bytes): segH | featH | sqF | slots
#define FEATH_OFF ((size_t)NPIX*SEGW*2)
#define SQF_OFF   (FEATH_OFF + (size_t)NPIX*FEATW*2)
#define SLOT_OFF  (SQF_OFF + (size_t)NPIX*4)

// ---------------------------------------------------------------------------
// Prep (R8 structure, unchanged): pixel-fast indexing, coalesced reads/writes.
// q<24 -> seg channel (2x2 avg pool * nearest ROI) as f16;
// q==24 -> 5 prescaled features (padded half8) + fp32 h = 0.5|v|^2 from the
// f16-ROUNDED v so E_ii == 0 exactly;  q==25, pl<64 -> zero slots.
// ---------------------------------------------------------------------------
__global__ __launch_bounds__(256) void crf_prep(const float* __restrict__ img,
                                                const float* __restrict__ seg,
                                                const float* __restrict__ roi,
                                                half_t* __restrict__ segH,
                                                half_t* __restrict__ featH,
                                                float* __restrict__ sqF,
                                                float* __restrict__ slots) {
    int g  = blockIdx.x * 256 + threadIdx.x;      // [0, 32*NPIX)
    int q  = g >> 14;                             // slow: record element
    int pl = g & (NPIX - 1);                      // fast: linear pixel
    int n  = pl >> 12;
    int p  = pl & (PPX - 1);
    int y = p >> 6, x = p & 63;
    int y2 = 2 * y, x2 = 2 * x;

    if (q < SEGW) {
        float v = 0.0f;
        if (q < KCH) {
            const float* s0 = seg + (((size_t)n * KCH + q) * HIN + y2) * WIN + x2;
            float r = roi[((size_t)n * HIN + y2) * WIN + x2];
            v = 0.25f * (s0[0] + s0[1] + s0[WIN] + s0[WIN + 1]) * r;
        }
        segH[(size_t)pl * SEGW + q] = (half_t)v;
    } else if (q == 24) {
        float fx = (float)x * (PRE2 / 50.0f);
        float fy = (float)y * (PRE2 / 50.0f);
        const size_t ib = (((size_t)n * CCH) * HIN + y2) * WIN + x2;
        float fr = img[ib]                         * (PRE2 / 0.15f);
        float fg = img[ib + (size_t)HIN * WIN]     * (PRE2 / 0.15f);
        float fb = img[ib + 2 * (size_t)HIN * WIN] * (PRE2 / 0.15f);
        half_t h0 = (half_t)fx, h1 = (half_t)fy, h2 = (half_t)fr,
               h3 = (half_t)fg, h4 = (half_t)fb;
        half8 fh = {h0, h1, h2, h3, h4, (half_t)0, (half_t)0, (half_t)0};
        *(half8*)(featH + (size_t)pl * FEATW) = fh;
        float a0 = (float)h0, a1 = (float)h1, a2 = (float)h2,
              a3 = (float)h3, a4 = (float)h4;
        sqF[pl] = 0.5f * (a0 * a0 + a1 * a1 + a2 * a2 + a3 * a3 + a4 * a4);
    } else if (q == 25) {
        if (pl < NSLOT) slots[pl * 16] = 0.0f;    // one slot per cacheline
    }
}

// ---------------------------------------------------------------------------
// Main (R8 structure with JCHUNK 256->128): finer blocks shrink the uniform
// block duration T_b; makespan ~ W/slots + T_b, and R8/R9/R11 all showed the
// T_b drain term (~8 us) dominating the residual.  4224 blocks of ~4 us.
// Per 16x16 tile: E = mfma(afeat,bfeat,c4) (c4 = -h_i - h_j),
// Gs = mfma(aseg,bseg,0), term = exp2(E)*Gs; diag blocks add {+1,0,-inf}
// in log2 space.  Partials -> 64 spread cachelines; crf_final sums.
// Triangular launch: I in [0,64) (64-px i-blocks), J in [I>>1, 32)
// (128-px j-chunks): sum = 1056 blocks/image.
// ---------------------------------------------------------------------------
__global__ __launch_bounds__(BLOCK, 8) void crf_main(const half_t* __restrict__ segH,
                                                     const half_t* __restrict__ featH,
                                                     const float* __restrict__ sqF,
                                                     float* __restrict__ slots) {
    const int bx = blockIdx.x;   // [0, 1056)
    const int n  = blockIdx.y;

    // triangular decode: group g = I>>1; per g: two I values x (32-g) J's
    // off(g) = 2*sum_{u<g}(32-u) = 64g - g(g-1)
    int g = 0;
#pragma unroll
    for (int t = 1; t < 32; ++t) {
        int off = 64 * t - t * (t - 1);
        if (bx >= off) g = t;
    }
    int rem = bx - (64 * g - g * (g - 1));
    int c   = 32 - g;
    int iq  = (rem >= c) ? 1 : 0;
    int I   = 2 * g + iq;
    int J   = g + (rem - iq * c);
    const bool diag = (J == g);            // j-chunk contains the i-block

    const half_t* segN  = segH  + (size_t)n * PPX * SEGW;
    const half_t* featN = featH + (size_t)n * PPX * FEATW;
    const float*  sqN   = sqF   + (size_t)n * PPX;

    __shared__ alignas(16) half_t segJ[JCHUNK * SEGW];    // 6 KB
    __shared__ alignas(16) half_t featJ[JCHUNK * FEATW];  // 2 KB
    __shared__ alignas(16) half_t zrow[8];                // 16 B of zeros
    __shared__ float hJ[JCHUNK];                          // 0.5 KB
    __shared__ float wsum[BLOCK / 64];

    const int tid  = threadIdx.x;
    const int lane = tid & 63, wv = tid >> 6;
    const int m = lane & 15, quad = lane >> 4;
    const int i0 = I * IBLK + wv * 16;
    const int j0 = J * JCHUNK;
    const int kq = (quad < 2) ? quad : 2;   // seg k-slice (quad3 -> zero row)

    half8 hz = {};

    // A-frags from global (reused over all 8 j-tiles)
    half8 aseg  = *(const half8*)(segN  + (size_t)(i0 + m) * SEGW + kq * 8);
    half8 afeat = *(const half8*)(featN + (size_t)(i0 + m) * FEATW);
    f32x4v hi   = *(const f32x4v*)(sqN + i0 + quad * 4);  // rows quad*4..+3
    if (quad == 3) aseg  = hz;
    if (quad != 0) afeat = hz;
    f32x4v nh = -hi;

    // stage j-chunk (flat coalesced 16B copies) + zero row
    {
        const f32x4v* gsrc = (const f32x4v*)(segN + (size_t)j0 * SEGW);
        f32x4v* ldst = (f32x4v*)segJ;
        ldst[tid] = gsrc[tid];                           // 256 of 384
        if (tid < 384 - 256) ldst[256 + tid] = gsrc[256 + tid];
        if (tid < 128)
            ((f32x4v*)featJ)[tid] = ((const f32x4v*)(featN + (size_t)j0 * FEATW))[tid];
        if (tid < 128) hJ[tid] = sqN[j0 + tid];
        if (tid < 8) zrow[tid] = (half_t)0;
    }
    __syncthreads();

    // per-lane B pointers: stride over j-tiles, or pinned to the zero row
    const half_t* bsp; int bstep;
    if (quad == 3) { bsp = zrow;                       bstep = 0; }
    else           { bsp = segJ + m * SEGW + quad * 8; bstep = 16 * SEGW; }
    const half_t* bfp; int fstep;
    if (quad == 0) { bfp = featJ + m * FEATW;          fstep = 16 * FEATW; }
    else           { bfp = zrow;                       fstep = 0; }

    float acc0 = 0.0f, acc1 = 0.0f, acc2 = 0.0f, acc3 = 0.0f;
    const f32x4v zero4 = {0.0f, 0.0f, 0.0f, 0.0f};

#pragma unroll 4
    for (int jt = 0; jt < JCHUNK / 16; ++jt) {
        half8 bseg = *(const half8*)bsp;  bsp += bstep;
        half8 bft  = *(const half8*)bfp;  bfp += fstep;
        float hc = hJ[jt * 16 + m];

        f32x4v c4 = {nh[0] - hc, nh[1] - hc, nh[2] - hc, nh[3] - hc};
        f32x4v E  = __builtin_amdgcn_mfma_f32_16x16x32_f16(afeat, bft, c4, 0, 0, 0);
        f32x4v Gs = __builtin_amdgcn_mfma_f32_16x16x32_f16(aseg, bseg, zero4, 0, 0, 0);

        if (!diag) {
            acc0 = fmaf(__builtin_amdgcn_exp2f(E[0]), Gs[0], acc0);
            acc1 = fmaf(__builtin_amdgcn_exp2f(E[1]), Gs[1], acc1);
            acc2 = fmaf(__builtin_amdgcn_exp2f(E[2]), Gs[2], acc2);
            acc3 = fmaf(__builtin_amdgcn_exp2f(E[3]), Gs[3], acc3);
        } else {
            const int jg = j0 + jt * 16 + m;
            const int ia = i0 + quad * 4;
            float s0 = (jg > ia)     ? 1.0f : ((jg == ia)     ? 0.0f : -100000.0f);
            float s1 = (jg > ia + 1) ? 1.0f : ((jg == ia + 1) ? 0.0f : -100000.0f);
            float s2 = (jg > ia + 2) ? 1.0f : ((jg == ia + 2) ? 0.0f : -100000.0f);
            float s3 = (jg > ia + 3) ? 1.0f : ((jg == ia + 3) ? 0.0f : -100000.0f);
            acc0 = fmaf(__builtin_amdgcn_exp2f(E[0] + s0), Gs[0], acc0);
            acc1 = fmaf(__builtin_amdgcn_exp2f(E[1] + s1), Gs[1], acc1);
            acc2 = fmaf(__builtin_amdgcn_exp2f(E[2] + s2), Gs[2], acc2);
            acc3 = fmaf(__builtin_amdgcn_exp2f(E[3] + s3), Gs[3], acc3);
        }
    }

    // reduce: thread -> wave -> block -> spread atomic slot
    float racc = (acc0 + acc1) + (acc2 + acc3);
#pragma unroll
    for (int off = 32; off > 0; off >>= 1) racc += __shfl_down(racc, off);
    if (lane == 0) wsum[wv] = racc;
    __syncthreads();
    if (tid == 0) {
        float s = wsum[0] + wsum[1] + wsum[2] + wsum[3];
        if (!diag) s *= 2.0f;              // strictly-upper counts (i,j)+(j,i)
        int slot = (bx + BPI * n) & (NSLOT - 1);
        atomicAdd(&slots[slot * 16], s);
    }
}

// ---------------------------------------------------------------------------
// Final: one wave sums the 64 slots and writes the scalar output.
// ---------------------------------------------------------------------------
__global__ __launch_bounds__(64) void crf_final(const float* __restrict__ slots,
                                                float* __restrict__ out) {
    int lane = threadIdx.x;
    float v = slots[lane * 16];
#pragma unroll
    for (int off = 32; off > 0; off >>= 1) v += __shfl_down(v, off);
    if (lane == 0) out[0] = v * (-5.0e-10f);   // WEIGHT * (-sum/NIMG)
}

extern "C" void kernel_launch(void* const* d_in, const int* in_sizes, int n_in,
                              void* d_out, int out_size, void* d_ws, size_t ws_size,
                              hipStream_t stream) {
    const float* img = (const float*)d_in[0];
    const float* seg = (const float*)d_in[1];
    const float* roi = (const float*)d_in[2];
    float* out = (float*)d_out;

    char* wsb = (char*)d_ws;                    // ~1.07 MB of ws used
    half_t* segH  = (half_t*)(wsb);
    half_t* featH = (half_t*)(wsb + FEATH_OFF);
    float*  sqF   = (float*)(wsb + SQF_OFF);
    float*  slots = (float*)(wsb + SLOT_OFF);

    crf_prep<<<(NPIX * 32) / 256, 256, 0, stream>>>(img, seg, roi,
                                                    segH, featH, sqF, slots);

    dim3 grid(BPI, NIMG);                       // 1056 triangular blocks/image
    crf_main<<<grid, BLOCK, 0, stream>>>(segH, featH, sqF, slots);

    crf_final<<<1, 64, 0, stream>>>(slots, out);
}